// Round 8
// baseline (233.379 us; speedup 1.0000x reference)
//
#include <hip/hip_runtime.h>

// DMoE (PLE/CGC) fused kernel for MI355X (gfx950).
// B=32768, D_IN=256, H=128, N_TASK=2, N_EXP=4, N_SHARE=4.
//
// R8: LDS-throughput attack (R7 post-mortem: LDS pipe ~100k cyc/CU vs MFMA
// 15k — bound by B-fragment re-reads + bank conflicts + t-split traffic).
//  - merged tasks, BM=128, grid 256 = 1 block/CU: weight traffic 190 MB dev.
//  - m_wave=64 (A resident, 128 VGPR): B-read duplication 2x (was 4x).
//  - B stored in global image PRE-SWIZZLED: row = h (256 B exactly, no pad),
//    64B chunk index ^= (h&3). Staging is a linear copy; in-phase
//    ds_read_b128 hits all 32 banks at 2 lanes/bank = conflict-free.
//  - reg-pipelined dist-1 double buffer (Bs0/Bs1 by unit parity), NC=2
//    weight copies, nontemporal x loads / out stores.

typedef __attribute__((ext_vector_type(8))) short short8;   // 8 x bf16
typedef __attribute__((ext_vector_type(4))) float float4v;  // MFMA C/D + nt

#define UNIT_B     32768      // half-expert: 128h x 128k bf16, swizzled
#define WAVE_B     4096       // UNIT_B / 8 waves
#define WGT_OFF_US 393216     // 24 units * 16384 ushorts
#define COPY_US    397312     // + 16*256 gate ushorts
#define COPY_B     794624

__device__ __forceinline__ unsigned short f2bf(float f) {
  unsigned u = __builtin_bit_cast(unsigned, f);
  u += 0x7FFFu + ((u >> 16) & 1u);   // round-to-nearest-even
  return (unsigned short)(u >> 16);
}

// ---------------------------------------------------------------------------
// Prep: WTs[c][e][kh] swizzled units + WgT[16][256] per copy.
__global__ __launch_bounds__(256)
void prep_kernel(const float* __restrict__ Ws,
                 const float* __restrict__ Wt,
                 const float* __restrict__ Wg,
                 unsigned short* __restrict__ WT, int NC) {
  int bid = blockIdx.x;
  int tid = threadIdx.x;
  if (bid < 96) {
    __shared__ float tile[64][65];
    int e  = bid >> 3;
    int kt = (bid >> 1) & 3;   // 64-wide k tile; kh = kt>>1
    int ht = bid & 1;          // h half
    const float* src = (e < 4) ? Ws + ((size_t)e << 15)
                               : Wt + ((size_t)(e - 4) << 15);
    int m = tid & 15, n = tid >> 4;
    #pragma unroll
    for (int i = 0; i < 4; ++i) {   // coalesced read of src[k][h]
      int kl = i * 16 + n;
      float4 v = *(const float4*)&src[(size_t)(kt * 64 + kl) * 128 + ht * 64 + m * 4];
      tile[kl][m * 4 + 0] = v.x;
      tile[kl][m * 4 + 1] = v.y;
      tile[kl][m * 4 + 2] = v.z;
      tile[kl][m * 4 + 3] = v.w;
    }
    __syncthreads();
    // write unit (e, kh): byte = h*256 + (chunk^(h&3))*64 + (k&31)*2
    int klocal = m * 4;                       // k within the 64-k tile
    int chunk  = (kt & 1) * 2 + (klocal >> 5);
    int kin    = klocal & 31;
    #pragma unroll
    for (int i = 0; i < 4; ++i) {
      int hl = i * 16 + n;
      int h  = ht * 64 + hl;
      ushort4 o;
      o.x = f2bf(tile[klocal + 0][hl]);
      o.y = f2bf(tile[klocal + 1][hl]);
      o.z = f2bf(tile[klocal + 2][hl]);
      o.w = f2bf(tile[klocal + 3][hl]);
      size_t us = (size_t)(e * 2 + (kt >> 1)) * 16384
                + (size_t)h * 128 + (size_t)((chunk ^ (h & 3)) * 32 + kin);
      for (int c = 0; c < NC; ++c)
        *(ushort4*)&WT[(size_t)c * COPY_US + us] = o;
    }
  } else {
    // gate weights WgT[n][256], n = t*8+g
    #pragma unroll
    for (int it = 0; it < 16; ++it) {
      int j = it * 256 + tid;
      int n = j >> 8, k = j & 255;
      int t = n >> 3, g = n & 7;
      unsigned short v = f2bf(Wg[(size_t)(t * 256 + k) * 8 + g]);
      for (int c = 0; c < NC; ++c)
        WT[(size_t)c * COPY_US + WGT_OFF_US + j] = v;
    }
  }
}

// ---------------------------------------------------------------------------
__global__ __launch_bounds__(512, 2)
void dmoe_main(const float* __restrict__ x,
               const unsigned short* __restrict__ WT,
               const float* __restrict__ b_share,
               const float* __restrict__ b_task,
               const float* __restrict__ b_gate,
               float* __restrict__ out, int NC) {
  __shared__ unsigned short Bs0[UNIT_B / 2];   // 32768 B
  __shared__ unsigned short Bs1[UNIT_B / 2];   // 32768 B
  __shared__ float gatesL[16 * 132];           // 8448 B
  __shared__ float biasLds[12 * 128];          // 6144 B

  const int tid  = threadIdx.x;
  const int lane = tid & 63;
  const int w    = tid >> 6;    // wave 0..7
  const int col  = lane & 15;
  const int quad = lane >> 4;
  const int mg   = w >> 2;      // rows [mg*64, mg*64+64)
  const int ng   = w & 3;       // h    [ng*32, ng*32+32)
  const int blk  = blockIdx.x;

  const char* WTc = (const char*)WT + (size_t)((blk >> 3) % NC) * COPY_B;

  // ---- issue unit-0 stage loads first (longest latency) ----
  uint4 p0, p1, p2, p3;
  {
    const char* g = WTc + w * WAVE_B + lane * 16;
    p0 = *(const uint4*)(g);
    p1 = *(const uint4*)(g + 1024);
    p2 = *(const uint4*)(g + 2048);
    p3 = *(const uint4*)(g + 3072);
  }

  // ---- A-fragments: 4 m-tiles x 8 k-chunks resident (nontemporal x) ----
  short8 A[4][8];
  {
    const float* xb = x + ((size_t)blk * 128 + mg * 64 + col) * 256 + quad * 8;
    #pragma unroll
    for (int mt = 0; mt < 4; ++mt) {
      const float* xr = xb + (size_t)mt * 16 * 256;
      #pragma unroll
      for (int kc = 0; kc < 8; ++kc) {
        float4v u = __builtin_nontemporal_load((const float4v*)(xr + kc * 32));
        float4v v = __builtin_nontemporal_load((const float4v*)(xr + kc * 32 + 4));
        short8 fr;
        fr[0] = (short)f2bf(u[0]); fr[1] = (short)f2bf(u[1]);
        fr[2] = (short)f2bf(u[2]); fr[3] = (short)f2bf(u[3]);
        fr[4] = (short)f2bf(v[0]); fr[5] = (short)f2bf(v[1]);
        fr[6] = (short)f2bf(v[2]); fr[7] = (short)f2bf(v[3]);
        A[mt][kc] = fr;
      }
    }
  }

  // ---- biases -> LDS ----
  for (int i = tid; i < 1536; i += 512)
    biasLds[i] = (i < 512) ? b_share[i] : b_task[i - 512];

  // ---- gates: 16 logit cols (col bit3 = task); all waves compute their
  //      mg rows, ng==0 waves write ----
  {
    const unsigned short* WgT = (const unsigned short*)(WTc + WGT_OFF_US * 2);
    const unsigned short* bp = WgT + (size_t)col * 256 + quad * 8;
    short8 Bg[8];
    #pragma unroll
    for (int kc = 0; kc < 8; ++kc) Bg[kc] = *(const short8*)(bp + kc * 32);
    float bg = b_gate[col];
    #pragma unroll
    for (int mt = 0; mt < 4; ++mt) {
      float4v ag = {0.f, 0.f, 0.f, 0.f};
      #pragma unroll
      for (int kc = 0; kc < 8; ++kc)
        ag = __builtin_amdgcn_mfma_f32_16x16x32_bf16(A[mt][kc], Bg[kc], ag, 0, 0, 0);
      #pragma unroll
      for (int r = 0; r < 4; ++r) {
        float vlog = ag[r] + bg;
        float m = vlog;                      // softmax over 8 cols per task
        m = fmaxf(m, __shfl_xor(m, 1));
        m = fmaxf(m, __shfl_xor(m, 2));
        m = fmaxf(m, __shfl_xor(m, 4));
        float p = __expf(vlog - m);
        float s = p;
        s += __shfl_xor(s, 1);
        s += __shfl_xor(s, 2);
        s += __shfl_xor(s, 4);
        if (ng == 0)
          gatesL[col * 132 + mg * 64 + mt * 16 + quad * 4 + r] = p / s;
      }
    }
  }

  // ---- deposit unit 0 into Bs0 (linear copy; swizzle is in the image) ----
  {
    char* l = (char*)Bs0 + w * WAVE_B + lane * 16;
    *(uint4*)(l)        = p0;
    *(uint4*)(l + 1024) = p1;
    *(uint4*)(l + 2048) = p2;
    *(uint4*)(l + 3072) = p3;
  }
  __syncthreads();

  // ---- accumulators ----
  float tw[2][4][2][4];   // [task][mt][nt][r]
  #pragma unroll
  for (int t = 0; t < 2; ++t)
    #pragma unroll
    for (int mt = 0; mt < 4; ++mt)
      #pragma unroll
      for (int nt = 0; nt < 2; ++nt)
        #pragma unroll
        for (int r = 0; r < 4; ++r)
          tw[t][mt][nt][r] = 0.f;

  float4v acc[4][2];

  // ---- unit loop: 12 experts x 2 k-halves; buffer = kh (compile-time) ----
  #pragma unroll 1
  for (int e = 0; e < 12; ++e) {
    #pragma unroll
    for (int kh = 0; kh < 2; ++kh) {
      const int u = e * 2 + kh;
      // prefetch next unit
      uint4 q0, q1, q2, q3;
      const bool doStage = (u < 23);
      if (doStage) {
        const char* g = WTc + (size_t)(u + 1) * UNIT_B + w * WAVE_B + lane * 16;
        q0 = *(const uint4*)(g);
        q1 = *(const uint4*)(g + 1024);
        q2 = *(const uint4*)(g + 2048);
        q3 = *(const uint4*)(g + 3072);
      }
      if (kh == 0) {
        #pragma unroll
        for (int mt = 0; mt < 4; ++mt)
          #pragma unroll
          for (int nt = 0; nt < 2; ++nt)
            acc[mt][nt] = (float4v){0.f, 0.f, 0.f, 0.f};
      }
      // compute this unit from Bs[kh]: h rows at 256 B, chunk ^= h&3
      {
        const char* Bb = (const char*)(kh ? Bs1 : Bs0);
        #pragma unroll
        for (int kc = 0; kc < 4; ++kc) {
          #pragma unroll
          for (int nt = 0; nt < 2; ++nt) {
            const int h = ng * 32 + nt * 16 + col;
            short8 bfr = *(const short8*)(Bb + h * 256
                                          + (kc ^ (h & 3)) * 64 + quad * 16);
            acc[0][nt] = __builtin_amdgcn_mfma_f32_16x16x32_bf16(
                A[0][kh * 4 + kc], bfr, acc[0][nt], 0, 0, 0);
            acc[1][nt] = __builtin_amdgcn_mfma_f32_16x16x32_bf16(
                A[1][kh * 4 + kc], bfr, acc[1][nt], 0, 0, 0);
            acc[2][nt] = __builtin_amdgcn_mfma_f32_16x16x32_bf16(
                A[2][kh * 4 + kc], bfr, acc[2][nt], 0, 0, 0);
            acc[3][nt] = __builtin_amdgcn_mfma_f32_16x16x32_bf16(
                A[3][kh * 4 + kc], bfr, acc[3][nt], 0, 0, 0);
          }
        }
      }
      // deposit prefetched unit into the other buffer
      if (doStage) {
        char* l = (char*)(kh ? Bs0 : Bs1) + w * WAVE_B + lane * 16;
        *(uint4*)(l)        = q0;
        *(uint4*)(l + 1024) = q1;
        *(uint4*)(l + 2048) = q2;
        *(uint4*)(l + 3072) = q3;
      }
      // epilogue after second half
      if (kh == 1) {
        float bias[2];
        #pragma unroll
        for (int nt = 0; nt < 2; ++nt)
          bias[nt] = biasLds[e * 128 + ng * 32 + nt * 16 + col];
        if (e < 4) {
          #pragma unroll
          for (int mt = 0; mt < 4; ++mt) {
            int rb = mg * 64 + mt * 16 + quad * 4;
            float4 g0 = *(const float4*)&gatesL[e * 132 + rb];
            float4 g1 = *(const float4*)&gatesL[(8 + e) * 132 + rb];
            #pragma unroll
            for (int nt = 0; nt < 2; ++nt)
              #pragma unroll
              for (int r = 0; r < 4; ++r) {
                float v = fmaxf(acc[mt][nt][r] + bias[nt], 0.f);
                tw[0][mt][nt][r] += ((const float*)&g0)[r] * v;
                tw[1][mt][nt][r] += ((const float*)&g1)[r] * v;
              }
          }
        } else {
          const int t  = (e - 4) >> 2;
          const int gc = t * 8 + 4 + ((e - 4) & 3);
          #pragma unroll
          for (int mt = 0; mt < 4; ++mt) {
            int rb = mg * 64 + mt * 16 + quad * 4;
            float4 g = *(const float4*)&gatesL[gc * 132 + rb];
            #pragma unroll
            for (int nt = 0; nt < 2; ++nt)
              #pragma unroll
              for (int r = 0; r < 4; ++r) {
                float v = fmaxf(acc[mt][nt][r] + bias[nt], 0.f);
                tw[t][mt][nt][r] += ((const float*)&g)[r] * v;
              }
          }
        }
      }
      __syncthreads();
    }
  }

  // ---- write towers (nontemporal): out[t][row][h] ----
  #pragma unroll
  for (int t = 0; t < 2; ++t)
    #pragma unroll
    for (int mt = 0; mt < 4; ++mt)
      #pragma unroll
      for (int r = 0; r < 4; ++r) {
        size_t row = (size_t)blk * 128 + mg * 64 + mt * 16 + quad * 4 + r;
        float* op = out + ((size_t)t << 22) + row * 128 + ng * 32;
        __builtin_nontemporal_store(tw[t][mt][0][r], op + col);
        __builtin_nontemporal_store(tw[t][mt][1][r], op + 16 + col);
      }
}

// ---------------------------------------------------------------------------
extern "C" void kernel_launch(void* const* d_in, const int* in_sizes, int n_in,
                              void* d_out, int out_size, void* d_ws, size_t ws_size,
                              hipStream_t stream) {
  const float* x       = (const float*)d_in[0];
  const float* W_share = (const float*)d_in[1];
  const float* b_share = (const float*)d_in[2];
  const float* W_task  = (const float*)d_in[3];
  const float* b_task  = (const float*)d_in[4];
  const float* W_gate  = (const float*)d_in[5];
  const float* b_gate  = (const float*)d_in[6];
  float* out = (float*)d_out;
  unsigned short* WT = (unsigned short*)d_ws;

  int NC = (int)(ws_size / (size_t)COPY_B);
  if (NC < 1) NC = 1;
  if (NC > 2) NC = 2;

  prep_kernel<<<97, 256, 0, stream>>>(W_share, W_task, W_gate, WT, NC);
  dmoe_main<<<256, 512, 0, stream>>>(x, WT, b_share, b_task, b_gate, out, NC);
}